// Round 1
// baseline (115.390 us; speedup 1.0000x reference)
//
#include <hip/hip_runtime.h>
#include <math.h>

// TripletLoss semi-hard mining, N=512, D=512, C=64.
// v10: single fused kernel. v9's distance pipeline (136 symmetric 32x32
// triangle tiles, bf16 hi/lo 3-MFMA Gram) is unchanged; mining is fused in
// via per-row-block completion counters:
//   - after writing tile+mirror, each block release-fences and increments
//     rowcnt[bi] (and rowcnt[bj] if off-diagonal); each 32-row block gets
//     exactly 16 contributions.
//   - the block that sees old==15 acquire-fences and mines those 32 rows
//     (8 waves x 4 rows), overlapped with other blocks' distance work.
//   - mining inner loop batches 4 positives per shuffle-reduce pass
//     (4 independent 6-deep fmin chains pipeline -> ~3x lower latency).
//   - loss/np accumulated atomically; done-counter (target 16) finalizes.
// ctrl zeroing via 80-B hipMemsetAsync (graph-capturable, stream-ordered).

#define NN 512
#define MARGIN_F 0.2f
#define LK 528                    // LDS row stride in shorts

typedef __attribute__((ext_vector_type(8))) short bf16x8;
typedef __attribute__((ext_vector_type(4))) float f32x4;

__device__ __forceinline__ unsigned short f2bf(float x){
    unsigned u = __float_as_uint(x);
    return (unsigned short)((u + 0x7FFFu + ((u >> 16) & 1u)) >> 16);   // RNE
}
__device__ __forceinline__ float bf2f(unsigned short h){
    return __uint_as_float(((unsigned)h) << 16);
}

// LDS byte offsets (distance phase)
#define SH_OFF   0                 // 4*32*528*2 = 135168
#define SNI_OFF  135168            // 32 f32
#define SNJ_OFF  135296            // 32 f32
#define SCR_OFF  135424            // 4*64*16 = 4096 (K-half partials)
#define TRP_OFF  139520            // 4 * 16*17*4 = 4352 (per-wave transpose)
#define SM_BYTES 143872
// mining-phase carve (distance-phase LDS is dead once mining starts)
#define WROW_OFF  0                // 8*512*4 = 16384 (per-wave row buffer)
#define SLBL_OFF  16384            // 512*4
#define PLIST_OFF 18432            // 8*128*2
#define PCNT_OFF  20480            // 8*4
#define MAB_OFF   20544            // 2*4

__global__ __launch_bounds__(512) void k_fused(
    const int* __restrict__ labels,
    const float* __restrict__ emb,
    float* __restrict__ Dm,
    int* __restrict__ ctrl,       // [0]=loss f32 [1]=np u32 [2]=done u32 [3..18]=rowcnt u32
    float* __restrict__ out)
{
    __shared__ __align__(16) char sm[SM_BYTES];
    short* sh  = (short*)(sm + SH_OFF);           // [4][32][LK] Ihi/Ilo/Jhi/Jlo
    float* snI = (float*)(sm + SNI_OFF);
    float* snJ = (float*)(sm + SNJ_OFF);
    f32x4* scr = (f32x4*)(sm + SCR_OFF);          // [4][64]
    float* trp = (float*)(sm + TRP_OFF);          // [4][16*17]

    const int tid  = threadIdx.x;
    const int wave = tid >> 6, lane = tid & 63;

    // triangle map: blockIdx.x in [0,136) -> (bi,bj), bi<=bj
    int t = blockIdx.x, bi = 0;
    #pragma unroll
    for (int r = 0; r < 16; ++r) {
        const int rowlen = 16 - r;
        if (t < rowlen) { bi = r; break; }
        t -= rowlen;
    }
    const int bj = bi + t;

    // ---- staging: 64 rows (32 I + 32 J) fp32 -> bf16 hi/lo + norms ----
    {
        const int row = tid >> 3;                 // 0..63
        const int s8  = tid & 7;
        const int isJ = row >> 5;                 // 0:I 1:J
        const int rl  = row & 31;
        const int grow = (isJ ? bj : bi) * 32 + rl;
        const int bhi = (isJ << 1), blo = bhi + 1;
        const float4* Ep = (const float4*)emb;    // 128 float4 per row
        float ss = 0.f;
        #pragma unroll
        for (int i = 0; i < 16; ++i) {
            const int c4 = s8 + (i << 3);         // 0..127
            const float4 v = Ep[(size_t)grow * 128 + c4];
            ss = fmaf(v.x, v.x, ss); ss = fmaf(v.y, v.y, ss);
            ss = fmaf(v.z, v.z, ss); ss = fmaf(v.w, v.w, ss);
            ushort4 h, l;
            h.x = f2bf(v.x); l.x = f2bf(v.x - bf2f(h.x));
            h.y = f2bf(v.y); l.y = f2bf(v.y - bf2f(h.y));
            h.z = f2bf(v.z); l.z = f2bf(v.z - bf2f(h.z));
            h.w = f2bf(v.w); l.w = f2bf(v.w - bf2f(h.w));
            *(ushort4*)(&sh[(bhi * 32 + rl) * LK + (c4 << 2)]) = h;
            *(ushort4*)(&sh[(blo * 32 + rl) * LK + (c4 << 2)]) = l;
        }
        ss += __shfl_xor(ss, 1, 64);
        ss += __shfl_xor(ss, 2, 64);
        ss += __shfl_xor(ss, 4, 64);
        if (s8 == 0) { if (isJ) snJ[rl] = ss; else snI[rl] = ss; }
    }
    __syncthreads();

    // ---- MFMA: quad = quadrant, khalf = K half ----
    const int quad = wave & 3, khalf = wave >> 2;
    const int rowb = (quad >> 1) << 4, colb = (quad & 1) << 4;
    const int fr = lane & 15;
    const int q4 = lane >> 4;                     // 0..3
    const int k0 = q4 << 3;
    f32x4 acc = {0.f, 0.f, 0.f, 0.f};
    #pragma unroll
    for (int t8 = 0; t8 < 8; ++t8) {
        const int k = k0 + (((khalf << 3) + t8) << 5);
        const bf16x8 ahi = *(const bf16x8*)(&sh[(0 * 32 + rowb + fr) * LK + k]);
        const bf16x8 alo = *(const bf16x8*)(&sh[(1 * 32 + rowb + fr) * LK + k]);
        const bf16x8 bhi = *(const bf16x8*)(&sh[(2 * 32 + colb + fr) * LK + k]);
        const bf16x8 blo = *(const bf16x8*)(&sh[(3 * 32 + colb + fr) * LK + k]);
        acc = __builtin_amdgcn_mfma_f32_16x16x32_bf16(ahi, bhi, acc, 0, 0, 0);
        acc = __builtin_amdgcn_mfma_f32_16x16x32_bf16(ahi, blo, acc, 0, 0, 0);
        acc = __builtin_amdgcn_mfma_f32_16x16x32_bf16(alo, bhi, acc, 0, 0, 0);
    }
    if (khalf == 1) scr[quad * 64 + lane] = acc;
    __syncthreads();
    if (khalf == 0) {
        const f32x4 other = scr[quad * 64 + lane];
        acc[0] += other[0]; acc[1] += other[1];
        acc[2] += other[2]; acc[3] += other[3];
        // C/D layout col=lane&15, row=(lane>>4)*4+reg (m89-verified)
        const int colg = bj * 32 + colb + fr;
        const float sc = snJ[colb + fr];
        const int rl0 = rowb + (q4 << 2);
        float dv[4];
        #pragma unroll
        for (int reg = 0; reg < 4; ++reg) {
            const int rl = rl0 + reg;
            const float d2 = snI[rl] + sc - 2.f * acc[reg];
            dv[reg] = sqrtf(fmaxf(d2, 0.f));
            Dm[(size_t)(bi * 32 + rl) * NN + colg] = dv[reg];
        }
        // mirror tile via per-wave 16x17 transpose (intra-wave LDS only)
        float* T = trp + quad * (16 * 17);
        #pragma unroll
        for (int reg = 0; reg < 4; ++reg)
            T[fr * 17 + (q4 << 2) + reg] = dv[reg];   // T[col][row] = d(row,col)
        #pragma unroll
        for (int reg = 0; reg < 4; ++reg) {
            const float m = T[((q4 << 2) + reg) * 17 + fr];   // d(fr, 4q+reg)
            const int mrow = bj * 32 + colb + (q4 << 2) + reg;
            const int mcol = bi * 32 + rowb + fr;
            Dm[(size_t)mrow * NN + mcol] = m;
        }
    }

    // ---- publish tiles (release), detect completed row-blocks ----
    __threadfence();                 // writeback XCD L2 (release): tiles visible device-wide
    __syncthreads();
    int* mab = (int*)(sm + MAB_OFF);
    unsigned* rowcnt = (unsigned*)(ctrl + 3);
    if (tid == 0) {
        int mA = -1, mB = -1;
        if (atomicAdd(&rowcnt[bi], 1u) == 15u) mA = bi;     // 16th contribution
        if (bj != bi && atomicAdd(&rowcnt[bj], 1u) == 15u) mB = bj;
        __threadfence();             // acquire: invalidate local L1/L2 before Dm reads
        mab[0] = mA; mab[1] = mB;
    }
    __syncthreads();
    const int mA = mab[0], mB = mab[1];
    if (mA < 0 && mB < 0) return;    // block-uniform exit

    // ---- mine completed row-block(s): 8 waves x 4 rows (v4 logic, 4-batched) ----
    float* wrow = (float*)(sm + WROW_OFF) + wave * 512;
    int*   slbl = (int*)(sm + SLBL_OFF);
    unsigned short* plist = (unsigned short*)(sm + PLIST_OFF) + wave * 128;
    int*   pcnt = (int*)(sm + PCNT_OFF);

    slbl[tid] = labels[tid];
    __syncthreads();

    float wloss = 0.f;
    unsigned wnp = 0u;
    for (int pass = 0; pass < 2; ++pass) {
        const int rb = pass ? mB : mA;
        if (rb < 0) continue;
        for (int r = 0; r < 4; ++r) {
            const int j = rb * 32 + (wave << 2) + r;
            const float4* rp = (const float4*)(Dm + (size_t)j * NN);
            const float4 va = rp[lane * 2], vb = rp[lane * 2 + 1];
            *(float4*)(&wrow[lane * 8])     = va;
            *(float4*)(&wrow[lane * 8 + 4]) = vb;
            float d[8] = {va.x, va.y, va.z, va.w, vb.x, vb.y, vb.z, vb.w};
            const int lj = slbl[j];
            int lb[8];
            #pragma unroll
            for (int m = 0; m < 8; ++m) lb[m] = slbl[lane * 8 + m];
            if (lane == 0) pcnt[wave] = 0;
            // in-order per-wave DS ops: reset visible before the atomics below
            #pragma unroll
            for (int m = 0; m < 8; ++m) {
                const int k = lane * 8 + m;
                if (k != j && lb[m] == lj) {
                    const int ix = atomicAdd(&pcnt[wave], 1);
                    plist[ix] = (unsigned short)k;
                }
            }
            // max over negatives: dpa-independent, reduce once per row
            float vmaxl = 0.f;
            #pragma unroll
            for (int m = 0; m < 8; ++m) if (lb[m] != lj) vmaxl = fmaxf(vmaxl, d[m]);
            #pragma unroll
            for (int o = 32; o > 0; o >>= 1) vmaxl = fmaxf(vmaxl, __shfl_xor(vmaxl, o, 64));
            const int np = pcnt[wave];
            // 4 positives per pass: 4 independent shuffle-min chains pipeline
            for (int p0 = 0; p0 < np; p0 += 4) {
                const int nn = np - p0;
                const float dp0 = wrow[plist[p0]];
                const float dp1 = (nn > 1) ? wrow[plist[p0 + 1]] : 3e30f;
                const float dp2 = (nn > 2) ? wrow[plist[p0 + 2]] : 3e30f;
                const float dp3 = (nn > 3) ? wrow[plist[p0 + 3]] : 3e30f;
                float vm0 = 1e30f, vm1 = 1e30f, vm2 = 1e30f, vm3 = 1e30f;
                #pragma unroll
                for (int m = 0; m < 8; ++m) {
                    const bool ng = (lb[m] != lj);
                    const float dm = d[m];
                    if (ng && dm > dp0) vm0 = fminf(vm0, dm);
                    if (ng && dm > dp1) vm1 = fminf(vm1, dm);
                    if (ng && dm > dp2) vm2 = fminf(vm2, dm);
                    if (ng && dm > dp3) vm3 = fminf(vm3, dm);
                }
                #pragma unroll
                for (int o = 32; o > 0; o >>= 1) {
                    vm0 = fminf(vm0, __shfl_xor(vm0, o, 64));
                    vm1 = fminf(vm1, __shfl_xor(vm1, o, 64));
                    vm2 = fminf(vm2, __shfl_xor(vm2, o, 64));
                    vm3 = fminf(vm3, __shfl_xor(vm3, o, 64));
                }
                if (lane == 0) {
                    float ngv = (vm0 < 1e29f) ? vm0 : vmaxl;
                    float tq  = MARGIN_F + dp0 - ngv;
                    if (tq > 0.f) wloss += tq;
                    if (nn > 1) { ngv = (vm1 < 1e29f) ? vm1 : vmaxl; tq = MARGIN_F + dp1 - ngv; if (tq > 0.f) wloss += tq; }
                    if (nn > 2) { ngv = (vm2 < 1e29f) ? vm2 : vmaxl; tq = MARGIN_F + dp2 - ngv; if (tq > 0.f) wloss += tq; }
                    if (nn > 3) { ngv = (vm3 < 1e29f) ? vm3 : vmaxl; tq = MARGIN_F + dp3 - ngv; if (tq > 0.f) wloss += tq; }
                }
            }
            if (lane == 0) wnp += (unsigned)np;
        }
    }
    if (lane == 0) {
        if (wloss != 0.f) atomicAdd((float*)&ctrl[0], wloss);
        if (wnp) atomicAdd((unsigned*)&ctrl[1], wnp);
    }
    __syncthreads();                 // barrier drains this block's atomics (vmcnt)
    if (tid == 0) {
        __threadfence();
        const int nfin = (mA >= 0) + (mB >= 0);
        for (int q = 0; q < nfin; ++q) {
            if (atomicAdd((unsigned*)&ctrl[2], 1u) == 15u) {   // 16th row-block done
                const float L = atomicAdd((float*)&ctrl[0], 0.f);
                const unsigned C = atomicAdd((unsigned*)&ctrl[1], 0u);
                out[0] = L / ((float)C + 1e-8f);
            }
        }
    }
}

extern "C" void kernel_launch(void* const* d_in, const int* in_sizes, int n_in,
                              void* d_out, int out_size, void* d_ws, size_t ws_size,
                              hipStream_t stream) {
    (void)in_sizes; (void)n_in; (void)out_size; (void)ws_size;
    const int* labels = (const int*)d_in[0];
    const float* emb  = (const float*)d_in[1];
    char* ws = (char*)d_ws;
    float* Dm   = (float*)ws;                     // 1 MB
    int*   ctrl = (int*)(ws + (1u << 20));        // 20 ints: loss/np/done/rowcnt[16]

    hipMemsetAsync(ctrl, 0, 80, stream);          // stream-ordered, graph-capturable
    k_fused<<<136, 512, 0, stream>>>(labels, emb, Dm, ctrl, (float*)d_out);
}

// Round 2
// 77.099 us; speedup vs baseline: 1.4966x; 1.4966x over previous
//
#include <hip/hip_runtime.h>
#include <math.h>

// TripletLoss semi-hard mining, N=512, D=512, C=64.
// v11: revert to v9 two-kernel structure (v10 fusion post-mortem: per-block
// device-scope fences = XCD-L2 writeback/invalidate, 66us of idle — a kernel
// boundary is far cheaper than cross-XCD coherence on CDNA4).
//   k_dist: 136 upper-triangle 32x32 tiles; stage 64 fp32 rows -> bf16 hi/lo
//           in LDS + norms; Gram via 3 MFMAs/k-step; K halved across wave
//           groups; writes tile + mirrored tile (per-wave 16x17 transpose).
//   k_mine: per-row mining (v4-verified semantics) with BATCH-4 positives:
//           4 independent 6-deep shuffle-min chains pipeline (~3x lower
//           serial latency than one-at-a-time). Done-counter finalize.

#define NN 512
#define MARGIN_F 0.2f
#define LK 528                    // LDS row stride in shorts

typedef __attribute__((ext_vector_type(8))) short bf16x8;
typedef __attribute__((ext_vector_type(4))) float f32x4;

__device__ __forceinline__ unsigned short f2bf(float x){
    unsigned u = __float_as_uint(x);
    return (unsigned short)((u + 0x7FFFu + ((u >> 16) & 1u)) >> 16);   // RNE
}
__device__ __forceinline__ float bf2f(unsigned short h){
    return __uint_as_float(((unsigned)h) << 16);
}

// LDS byte offsets
#define SH_OFF   0                 // 4*32*528*2 = 135168
#define SNI_OFF  135168            // 32 f32
#define SNJ_OFF  135296            // 32 f32
#define SCR_OFF  135424            // 4*64*16 = 4096 (K-half partials)
#define TRP_OFF  139520            // 4 * 16*17*4 = 4352 (per-wave transpose)
#define SM_BYTES 143872

// ---------------- k_dist: symmetric distance tiles ----------------
__global__ __launch_bounds__(512) void k_dist(
    const float* __restrict__ emb,
    float* __restrict__ Dm,
    int* __restrict__ ctrl)        // [0]=loss f32, [1]=cnt u32, [2]=done u32
{
    __shared__ __align__(16) char sm[SM_BYTES];
    short* sh  = (short*)(sm + SH_OFF);           // [4][32][LK] Ihi/Ilo/Jhi/Jlo
    float* snI = (float*)(sm + SNI_OFF);
    float* snJ = (float*)(sm + SNJ_OFF);
    f32x4* scr = (f32x4*)(sm + SCR_OFF);          // [4][64]
    float* trp = (float*)(sm + TRP_OFF);          // [4][16*17]

    const int tid  = threadIdx.x;
    const int wave = tid >> 6, lane = tid & 63;

    // triangle map: blockIdx.x in [0,136) -> (bi,bj), bi<=bj
    int t = blockIdx.x, bi = 0;
    #pragma unroll
    for (int r = 0; r < 16; ++r) {
        const int rowlen = 16 - r;
        if (t < rowlen) { bi = r; break; }
        t -= rowlen;
    }
    const int bj = bi + t;

    if (blockIdx.x == 0 && tid < 3) ctrl[tid] = 0;

    // ---- staging: 64 rows (32 I + 32 J) fp32 -> bf16 hi/lo + norms ----
    {
        const int row = tid >> 3;                 // 0..63
        const int s8  = tid & 7;
        const int isJ = row >> 5;                 // 0:I 1:J
        const int rl  = row & 31;
        const int grow = (isJ ? bj : bi) * 32 + rl;
        const int bhi = (isJ << 1), blo = bhi + 1;
        const float4* Ep = (const float4*)emb;    // 128 float4 per row
        float ss = 0.f;
        #pragma unroll
        for (int i = 0; i < 16; ++i) {
            const int c4 = s8 + (i << 3);         // 0..127
            const float4 v = Ep[(size_t)grow * 128 + c4];
            ss = fmaf(v.x, v.x, ss); ss = fmaf(v.y, v.y, ss);
            ss = fmaf(v.z, v.z, ss); ss = fmaf(v.w, v.w, ss);
            ushort4 h, l;
            h.x = f2bf(v.x); l.x = f2bf(v.x - bf2f(h.x));
            h.y = f2bf(v.y); l.y = f2bf(v.y - bf2f(h.y));
            h.z = f2bf(v.z); l.z = f2bf(v.z - bf2f(h.z));
            h.w = f2bf(v.w); l.w = f2bf(v.w - bf2f(h.w));
            *(ushort4*)(&sh[(bhi * 32 + rl) * LK + (c4 << 2)]) = h;
            *(ushort4*)(&sh[(blo * 32 + rl) * LK + (c4 << 2)]) = l;
        }
        ss += __shfl_xor(ss, 1, 64);
        ss += __shfl_xor(ss, 2, 64);
        ss += __shfl_xor(ss, 4, 64);
        if (s8 == 0) { if (isJ) snJ[rl] = ss; else snI[rl] = ss; }
    }
    __syncthreads();

    // ---- MFMA: quad = quadrant, khalf = K half ----
    const int quad = wave & 3, khalf = wave >> 2;
    const int rowb = (quad >> 1) << 4, colb = (quad & 1) << 4;
    const int fr = lane & 15;
    const int q4 = lane >> 4;                     // 0..3
    const int k0 = q4 << 3;
    f32x4 acc = {0.f, 0.f, 0.f, 0.f};
    #pragma unroll
    for (int t8 = 0; t8 < 8; ++t8) {
        const int k = k0 + (((khalf << 3) + t8) << 5);
        const bf16x8 ahi = *(const bf16x8*)(&sh[(0 * 32 + rowb + fr) * LK + k]);
        const bf16x8 alo = *(const bf16x8*)(&sh[(1 * 32 + rowb + fr) * LK + k]);
        const bf16x8 bhi = *(const bf16x8*)(&sh[(2 * 32 + colb + fr) * LK + k]);
        const bf16x8 blo = *(const bf16x8*)(&sh[(3 * 32 + colb + fr) * LK + k]);
        acc = __builtin_amdgcn_mfma_f32_16x16x32_bf16(ahi, bhi, acc, 0, 0, 0);
        acc = __builtin_amdgcn_mfma_f32_16x16x32_bf16(ahi, blo, acc, 0, 0, 0);
        acc = __builtin_amdgcn_mfma_f32_16x16x32_bf16(alo, bhi, acc, 0, 0, 0);
    }
    if (khalf == 1) scr[quad * 64 + lane] = acc;
    __syncthreads();
    if (khalf == 0) {
        const f32x4 other = scr[quad * 64 + lane];
        acc[0] += other[0]; acc[1] += other[1];
        acc[2] += other[2]; acc[3] += other[3];
        // C/D layout col=lane&15, row=(lane>>4)*4+reg (m89-verified)
        const int colg = bj * 32 + colb + fr;
        const float sc = snJ[colb + fr];
        const int rl0 = rowb + (q4 << 2);
        float dv[4];
        #pragma unroll
        for (int reg = 0; reg < 4; ++reg) {
            const int rl = rl0 + reg;
            const float d2 = snI[rl] + sc - 2.f * acc[reg];
            dv[reg] = sqrtf(fmaxf(d2, 0.f));
            Dm[(size_t)(bi * 32 + rl) * NN + colg] = dv[reg];
        }
        // mirror tile via per-wave 16x17 transpose (intra-wave LDS only)
        float* T = trp + quad * (16 * 17);
        #pragma unroll
        for (int reg = 0; reg < 4; ++reg)
            T[fr * 17 + (q4 << 2) + reg] = dv[reg];   // T[col][row] = d(row,col)
        #pragma unroll
        for (int reg = 0; reg < 4; ++reg) {
            const float m = T[((q4 << 2) + reg) * 17 + fr];   // d(fr, 4q+reg)
            const int mrow = bj * 32 + colb + (q4 << 2) + reg;
            const int mcol = bi * 32 + rowb + fr;
            Dm[(size_t)mrow * NN + mcol] = m;
        }
    }
}

// ---------------- k_mine: mining + finalize (v4 semantics, batch-4) ---------
__global__ __launch_bounds__(256) void k_mine(
    const int* __restrict__ labels,
    const float* __restrict__ Dm,
    float* __restrict__ accums,          // [0]=loss [1]=cnt(u32) [2]=done(u32)
    float* __restrict__ out,
    int nblocks)
{
    __shared__ int slbl[NN];
    __shared__ float drow[4][NN];
    __shared__ unsigned short plist[4][128];
    __shared__ int pcnt[4];

    const int tid = threadIdx.x, wave = tid >> 6, lane = tid & 63;
    const int j = blockIdx.x * 4 + wave;

    slbl[tid] = labels[tid];
    slbl[tid + 256] = labels[tid + 256];
    if (tid < 4) pcnt[tid] = 0;
    __syncthreads();

    // distance row j: 8 values per lane in registers + LDS copy for dpa lookups
    const float4* rp = (const float4*)(Dm + (size_t)j * NN);
    const float4 va = rp[lane * 2], vb = rp[lane * 2 + 1];
    *(float4*)(&drow[wave][lane * 8]) = va;
    *(float4*)(&drow[wave][lane * 8 + 4]) = vb;
    float d[8] = {va.x, va.y, va.z, va.w, vb.x, vb.y, vb.z, vb.w};
    const int lj = slbl[j];
    int lb[8];
    #pragma unroll
    for (int m = 0; m < 8; ++m) lb[m] = slbl[lane * 8 + m];

    // positive list (wave-local LDS; in-order per-wave DS ops)
    #pragma unroll
    for (int m = 0; m < 8; ++m){
        const int k = lane * 8 + m;
        if (k != j && lb[m] == lj){
            const int ix = atomicAdd(&pcnt[wave], 1);
            plist[wave][ix] = (unsigned short)k;
        }
    }
    // max over negatives: dpa-independent, reduce once per row
    float vmaxl = 0.f;
    #pragma unroll
    for (int m = 0; m < 8; ++m) if (lb[m] != lj) vmaxl = fmaxf(vmaxl, d[m]);
    #pragma unroll
    for (int o = 32; o > 0; o >>= 1) vmaxl = fmaxf(vmaxl, __shfl_xor(vmaxl, o, 64));

    const int np = pcnt[wave];
    float wloss = 0.f;
    // 4 positives per pass: 4 independent shuffle-min chains pipeline
    for (int p0 = 0; p0 < np; p0 += 4){
        const int nn = np - p0;
        const float dp0 = drow[wave][plist[wave][p0]];
        const float dp1 = (nn > 1) ? drow[wave][plist[wave][p0 + 1]] : 3e30f;
        const float dp2 = (nn > 2) ? drow[wave][plist[wave][p0 + 2]] : 3e30f;
        const float dp3 = (nn > 3) ? drow[wave][plist[wave][p0 + 3]] : 3e30f;
        float vm0 = 1e30f, vm1 = 1e30f, vm2 = 1e30f, vm3 = 1e30f;
        #pragma unroll
        for (int m = 0; m < 8; ++m){
            const bool ng = (lb[m] != lj);
            const float dm = d[m];
            if (ng && dm > dp0) vm0 = fminf(vm0, dm);
            if (ng && dm > dp1) vm1 = fminf(vm1, dm);
            if (ng && dm > dp2) vm2 = fminf(vm2, dm);
            if (ng && dm > dp3) vm3 = fminf(vm3, dm);
        }
        #pragma unroll
        for (int o = 32; o > 0; o >>= 1){
            vm0 = fminf(vm0, __shfl_xor(vm0, o, 64));
            vm1 = fminf(vm1, __shfl_xor(vm1, o, 64));
            vm2 = fminf(vm2, __shfl_xor(vm2, o, 64));
            vm3 = fminf(vm3, __shfl_xor(vm3, o, 64));
        }
        if (lane == 0){
            float ngv = (vm0 < 1e29f) ? vm0 : vmaxl;
            float tq  = MARGIN_F + dp0 - ngv;
            if (tq > 0.f) wloss += tq;
            if (nn > 1) { ngv = (vm1 < 1e29f) ? vm1 : vmaxl; tq = MARGIN_F + dp1 - ngv; if (tq > 0.f) wloss += tq; }
            if (nn > 2) { ngv = (vm2 < 1e29f) ? vm2 : vmaxl; tq = MARGIN_F + dp2 - ngv; if (tq > 0.f) wloss += tq; }
            if (nn > 3) { ngv = (vm3 < 1e29f) ? vm3 : vmaxl; tq = MARGIN_F + dp3 - ngv; if (tq > 0.f) wloss += tq; }
        }
    }
    if (lane == 0){
        if (wloss != 0.f) atomicAdd(&accums[0], wloss);
        if (np) atomicAdd((unsigned int*)&accums[1], (unsigned int)np);
    }
    __syncthreads();
    if (tid == 0){
        __threadfence();
        const unsigned old = atomicAdd((unsigned int*)&accums[2], 1u);
        if (old == (unsigned)(nblocks - 1)){
            const float L = atomicAdd(&accums[0], 0.f);
            const unsigned C = atomicAdd((unsigned int*)&accums[1], 0u);
            out[0] = L / ((float)C + 1e-8f);
        }
    }
}

extern "C" void kernel_launch(void* const* d_in, const int* in_sizes, int n_in,
                              void* d_out, int out_size, void* d_ws, size_t ws_size,
                              hipStream_t stream) {
    (void)in_sizes; (void)n_in; (void)out_size; (void)ws_size;
    const int* labels = (const int*)d_in[0];
    const float* emb  = (const float*)d_in[1];
    char* ws = (char*)d_ws;
    float* Dm   = (float*)ws;                     // 1 MB
    int*   ctrl = (int*)(ws + (1u << 20));        // 3 ints

    k_dist<<<136, 512, 0, stream>>>(emb, Dm, ctrl);
    k_mine<<<128, 256, 0, stream>>>(labels, Dm, (float*)ctrl, (float*)d_out, 128);
}